// Round 1
// baseline (1071.462 us; speedup 1.0000x reference)
//
#include <hip/hip_runtime.h>

#define N_NODES 100000
#define N_EDGES 1600000
#define D 64

// ---------------------------------------------------------------------------
// K2: edge scatter. One wave (64 lanes) per edge; lane c handles column c.
// emb row read is one coalesced 256B load; 64 consecutive f32 atomics into
// acc[dst]. unsafeAtomicAdd -> hardware global_atomic_add_f32 (plain
// atomicAdd may lower to a CAS loop without -munsafe-fp-atomics).
// ---------------------------------------------------------------------------
__global__ __launch_bounds__(256) void scatter_kernel(
    const float* __restrict__ emb,
    const int* __restrict__ edge_src,
    const int* __restrict__ edge_dst,
    float* __restrict__ acc) {
    int gid = blockIdx.x * 256 + threadIdx.x;
    int e = gid >> 6;     // edge index (grid sized exactly: N_EDGES*64 threads)
    int c = gid & 63;     // column
    int s = edge_src[e];  // same address across the wave -> broadcast load
    int d = edge_dst[e];
    unsafeAtomicAdd(&acc[d * D + c], emb[s * D + c]);
}

// ---------------------------------------------------------------------------
// K4: final pass. Per 64-node tile:
//   z[v][o] = sum_k feat[v][k]*W1[o][k] + nbr[v][k]*W2[o][k]
//   u = relu(z + b1[o] + b2[o]); out[o] += sum_v u
// Layout: lane = node (64 nodes/tile), wave w owns output cols [16w,16w+16).
// feat/nbr tiles staged TRANSPOSED in LDS with stride 65 (conflict-free:
// bank = (k*65+lane)%32 = (k+lane)%32). W indices go through readfirstlane
// so W1/W2 loads are scalar (s_load) and FMA reads them as SGPR operands.
// ---------------------------------------------------------------------------
__global__ __launch_bounds__(256) void final_kernel(
    const float* __restrict__ feat,
    const float* __restrict__ acc,
    const float* __restrict__ W1,
    const float* __restrict__ b1,
    const float* __restrict__ W2,
    const float* __restrict__ b2,
    float* __restrict__ out) {
    __shared__ float ft[64][65];  // [k][node]
    __shared__ float nt[64][65];

    const int tid  = threadIdx.x;
    const int lane = tid & 63;
    const int wave = tid >> 6;
    const int o_base = __builtin_amdgcn_readfirstlane(wave * 16);

    float sums[16];
#pragma unroll
    for (int j = 0; j < 16; ++j) sums[j] = 0.f;

    for (int tile = blockIdx.x; tile * 64 < N_NODES; tile += gridDim.x) {
        const int node0 = tile * 64;
        __syncthreads();  // protect LDS reuse across grid-stride iterations

        // Stage 64x64 tiles, transposed. Wave-coherent coalesced global reads:
        // within a wave, node fixed, c = lane runs 0..63 (256B contiguous).
#pragma unroll 4
        for (int it = 0; it < 16; ++it) {
            const int r = wave + it * 4;  // node-in-tile 0..63
            const int c = lane;           // feature index
            const int node = node0 + r;
            float fv = 0.f, nv = 0.f;
            if (node < N_NODES) {
                fv = feat[node * D + c];
                nv = acc[node * D + c];
            }
            ft[c][r] = fv;  // lanes write stride-65 -> conflict-free
            nt[c][r] = nv;
        }
        __syncthreads();

        float z[16];
#pragma unroll
        for (int j = 0; j < 16; ++j) z[j] = 0.f;

        for (int k = 0; k < D; ++k) {
            const float f  = ft[k][lane];  // lanes consecutive -> conflict-free
            const float nb = nt[k][lane];
#pragma unroll
            for (int j = 0; j < 16; ++j) {
                z[j] += f * W1[(o_base + j) * D + k];
                z[j] += nb * W2[(o_base + j) * D + k];
            }
        }

        const int node = node0 + lane;
        if (node < N_NODES) {
#pragma unroll
            for (int j = 0; j < 16; ++j) {
                const float u = z[j] + b1[o_base + j] + b2[o_base + j];
                sums[j] += (u > 0.f) ? u : 0.f;
            }
        }
    }

    // Reduce each column-partial across the 64 lanes, one atomic per column.
#pragma unroll
    for (int j = 0; j < 16; ++j) {
        float v = sums[j];
        for (int off = 32; off > 0; off >>= 1) v += __shfl_down(v, off);
        if (lane == 0) unsafeAtomicAdd(&out[o_base + j], v);
    }
}

extern "C" void kernel_launch(void* const* d_in, const int* in_sizes, int n_in,
                              void* d_out, int out_size, void* d_ws, size_t ws_size,
                              hipStream_t stream) {
    const float* feat = (const float*)d_in[0];
    const float* emb  = (const float*)d_in[1];
    const float* W1   = (const float*)d_in[2];
    const float* b1   = (const float*)d_in[3];
    const float* W2   = (const float*)d_in[4];
    const float* b2   = (const float*)d_in[5];
    const int* edge_src = (const int*)d_in[6];
    const int* edge_dst = (const int*)d_in[7];
    float* out = (float*)d_out;

    float* acc = (float*)d_ws;  // N_NODES * D floats = 25.6 MB of scratch

    // acc is re-poisoned to 0xAA before every timed launch -> re-zero here.
    hipMemsetAsync(acc, 0, (size_t)N_NODES * D * sizeof(float), stream);

    // One wave per edge: N_EDGES * 64 threads exactly.
    const int scatter_blocks = (N_EDGES * 64) / 256;  // 400000
    scatter_kernel<<<scatter_blocks, 256, 0, stream>>>(emb, edge_src, edge_dst, acc);

    hipMemsetAsync(out, 0, D * sizeof(float), stream);

    const int n_tiles = (N_NODES + 63) / 64;  // 1563
    final_kernel<<<n_tiles, 256, 0, stream>>>(feat, acc, W1, b1, W2, b2, out);
}

// Round 3
// 907.347 us; speedup vs baseline: 1.1809x; 1.1809x over previous
//
#include <hip/hip_runtime.h>

#define N_NODES 100000
#define N_EDGES 1600000
#define D 64
#define CAP 64        // slot cap per node; Poisson(16) deg, P(>64) astronomically small
#define OVF_CAP 8192  // overflow edge list capacity (practically unused)

// ws layout (bytes):
//   cnt      @ 0          : N_NODES int          (0.4 MB)
//   slots    @ 401408     : N_NODES*CAP int      (25.6 MB)  256B-aligned rows
//   acc      @ 26001408   : N_NODES*D float      (25.6 MB)
//   ovf_cnt  @ 51601408   : int
//   ovf      @ 51601424   : OVF_CAP int2
#define WS_SLOTS_OFF  401408
#define WS_ACC_OFF    26001408
#define WS_OVFC_OFF   51601408
#define WS_OVF_OFF    51601424
#define WS_NEEDED     (51601424 + OVF_CAP * 8)

// ---------------------------------------------------------------------------
// Build capped CSR: per edge, reserve a slot in dst's row. 1.6M int atomics
// (~16-way contention per node) instead of 102.4M f32 atomics.
// ---------------------------------------------------------------------------
__global__ __launch_bounds__(256) void fill_kernel(
    const int* __restrict__ edge_src, const int* __restrict__ edge_dst,
    int* __restrict__ cnt, int* __restrict__ slots,
    int* __restrict__ ovf_cnt, int2* __restrict__ ovf) {
    int e = blockIdx.x * 256 + threadIdx.x;  // grid sized exactly
    int s = edge_src[e];
    int d = edge_dst[e];
    int pos = atomicAdd(&cnt[d], 1);
    if (pos < CAP) {
        slots[d * CAP + pos] = s;
    } else {
        int i = atomicAdd(ovf_cnt, 1);
        if (i < OVF_CAP) ovf[i] = make_int2(s, d);
    }
}

// ---------------------------------------------------------------------------
// Atomic-free gather: one wave per node. One coalesced 256B read grabs the
// node's slot row; __shfl broadcasts each src; emb row reads are wave-uniform
// 256B loads (emb is 25.6MB -> L3-resident). Overwrites acc (no memset).
// 4-wide unroll keeps 4 independent row loads in flight.
// ---------------------------------------------------------------------------
__global__ __launch_bounds__(256) void gather_kernel(
    const float* __restrict__ emb, const int* __restrict__ cnt,
    const int* __restrict__ slots, float* __restrict__ acc) {
    const int lane = threadIdx.x & 63;
    const int wave = threadIdx.x >> 6;
    const int v = blockIdx.x * 4 + wave;  // grid = N_NODES/4 exactly
    int deg = cnt[v];
    if (deg > CAP) deg = CAP;
    const int si = slots[v * CAP + lane];  // coalesced; lanes >= deg unused
    float sum = 0.f;
    int e = 0;
    for (; e + 4 <= deg; e += 4) {
        int s0 = __shfl(si, e);
        int s1 = __shfl(si, e + 1);
        int s2 = __shfl(si, e + 2);
        int s3 = __shfl(si, e + 3);
        float a0 = emb[s0 * D + lane];
        float a1 = emb[s1 * D + lane];
        float a2 = emb[s2 * D + lane];
        float a3 = emb[s3 * D + lane];
        sum += a0; sum += a1; sum += a2; sum += a3;
    }
    for (; e < deg; ++e) sum += emb[__shfl(si, e) * D + lane];
    acc[v * D + lane] = sum;
}

// Overflow edges (normally zero): runs AFTER gather, atomically adds into acc.
__global__ void ovf_kernel(const float* __restrict__ emb,
                           const int* __restrict__ ovf_cnt,
                           const int2* __restrict__ ovf,
                           float* __restrict__ acc) {
    int n = *ovf_cnt;
    if (n > OVF_CAP) n = OVF_CAP;
    int lane = threadIdx.x;
    for (int i = 0; i < n; ++i) {
        int2 e = ovf[i];
        unsafeAtomicAdd(&acc[e.y * D + lane], emb[e.x * D + lane]);
    }
}

// ---------------------------------------------------------------------------
// Fallback scatter (only if ws_size < WS_NEEDED): one wave per edge, 64 f32
// hardware atomics into acc. (Round-1 path.)
// ---------------------------------------------------------------------------
__global__ __launch_bounds__(256) void scatter_kernel(
    const float* __restrict__ emb,
    const int* __restrict__ edge_src, const int* __restrict__ edge_dst,
    float* __restrict__ acc) {
    int gid = blockIdx.x * 256 + threadIdx.x;
    int e = gid >> 6;
    int c = gid & 63;
    int s = edge_src[e];
    int d = edge_dst[e];
    unsafeAtomicAdd(&acc[d * D + c], emb[s * D + c]);
}

// ---------------------------------------------------------------------------
// Final pass. Per 64-node tile: z = feat@W1^T + nbr@W2^T; relu(z+b); column
// sums -> out. W1/W2 staged into LDS once per block (EXACTLY 1024 float4
// each — R2 bug was 2048: OOB read of W1 and w1s overflow clobbering w2s)
// and read as wave-uniform float4 broadcasts (conflict-free).
// ft/nt transposed [k][node] stride 65: staging writes 2-way bank alias
// (free, m136), compute reads lane-consecutive (conflict-free).
// ---------------------------------------------------------------------------
__global__ __launch_bounds__(256) void final_kernel(
    const float* __restrict__ feat, const float* __restrict__ acc,
    const float* __restrict__ W1, const float* __restrict__ b1,
    const float* __restrict__ W2, const float* __restrict__ b2,
    float* __restrict__ out) {
    __shared__ float ft[64][65];   // [k][node]
    __shared__ float nt[64][65];
    __shared__ float w1s[64 * 64]; // [o][k], read via uniform float4
    __shared__ float w2s[64 * 64];

    const int tid  = threadIdx.x;
    const int lane = tid & 63;
    const int wave = tid >> 6;
    const int ob   = wave * 16;  // this wave's output-column base
    const int node0 = blockIdx.x * 64;

    // Stage W1/W2: 64*64 floats = 1024 float4 each; 4 per thread, coalesced.
    {
        const float4* W1v = (const float4*)W1;
        const float4* W2v = (const float4*)W2;
        float4* w1v = (float4*)w1s;
        float4* w2v = (float4*)w2s;
#pragma unroll
        for (int i = 0; i < 4; ++i) {
            int idx = tid + i * 256;  // 0..1023
            w1v[idx] = W1v[idx];
            w2v[idx] = W2v[idx];
        }
    }

    // Stage feat/acc tiles, transposed. Within a wave: node fixed, c=lane ->
    // 256B coalesced global reads.
#pragma unroll 4
    for (int it = 0; it < 16; ++it) {
        const int r = wave + it * 4;
        const int node = node0 + r;
        float fv = 0.f, nv = 0.f;
        if (node < N_NODES) {
            fv = feat[node * D + lane];
            nv = acc[node * D + lane];
        }
        ft[lane][r] = fv;
        nt[lane][r] = nv;
    }
    __syncthreads();

    float z[16];
#pragma unroll
    for (int j = 0; j < 16; ++j) z[j] = 0.f;

    for (int k = 0; k < D; k += 4) {
        const float f0 = ft[k + 0][lane];
        const float f1 = ft[k + 1][lane];
        const float f2 = ft[k + 2][lane];
        const float f3 = ft[k + 3][lane];
        const float n0 = nt[k + 0][lane];
        const float n1 = nt[k + 1][lane];
        const float n2 = nt[k + 2][lane];
        const float n3 = nt[k + 3][lane];
#pragma unroll
        for (int j = 0; j < 16; ++j) {
            const float4 w1 = *(const float4*)&w1s[(ob + j) * 64 + k];
            const float4 w2 = *(const float4*)&w2s[(ob + j) * 64 + k];
            z[j] += f0 * w1.x + f1 * w1.y + f2 * w1.z + f3 * w1.w
                  + n0 * w2.x + n1 * w2.y + n2 * w2.z + n3 * w2.w;
        }
    }

    // Bias + ReLU + per-node accumulate (guard OOB nodes: bias alone can be
    // positive and must NOT contribute).
    float sums[16];
    const int node = node0 + lane;
#pragma unroll
    for (int j = 0; j < 16; ++j) {
        float u = z[j] + b1[ob + j] + b2[ob + j];
        u = (u > 0.f) ? u : 0.f;
        sums[j] = (node < N_NODES) ? u : 0.f;
    }

    // Reduce across 64 lanes, one atomic per output column per block.
#pragma unroll
    for (int j = 0; j < 16; ++j) {
        float v = sums[j];
        for (int off = 32; off > 0; off >>= 1) v += __shfl_down(v, off);
        if (lane == 0) unsafeAtomicAdd(&out[ob + j], v);
    }
}

extern "C" void kernel_launch(void* const* d_in, const int* in_sizes, int n_in,
                              void* d_out, int out_size, void* d_ws, size_t ws_size,
                              hipStream_t stream) {
    const float* feat = (const float*)d_in[0];
    const float* emb  = (const float*)d_in[1];
    const float* W1   = (const float*)d_in[2];
    const float* b1   = (const float*)d_in[3];
    const float* W2   = (const float*)d_in[4];
    const float* b2   = (const float*)d_in[5];
    const int* edge_src = (const int*)d_in[6];
    const int* edge_dst = (const int*)d_in[7];
    float* out = (float*)d_out;
    char* ws = (char*)d_ws;

    hipMemsetAsync(out, 0, D * sizeof(float), stream);

    if (ws_size >= (size_t)WS_NEEDED) {
        int*  cnt     = (int*)ws;
        int*  slots   = (int*)(ws + WS_SLOTS_OFF);
        float* acc    = (float*)(ws + WS_ACC_OFF);
        int*  ovf_cnt = (int*)(ws + WS_OVFC_OFF);
        int2* ovf     = (int2*)(ws + WS_OVF_OFF);

        hipMemsetAsync(cnt, 0, N_NODES * sizeof(int), stream);
        hipMemsetAsync(ovf_cnt, 0, sizeof(int), stream);

        fill_kernel<<<N_EDGES / 256, 256, 0, stream>>>(edge_src, edge_dst,
                                                       cnt, slots, ovf_cnt, ovf);
        gather_kernel<<<N_NODES / 4, 256, 0, stream>>>(emb, cnt, slots, acc);
        ovf_kernel<<<1, 64, 0, stream>>>(emb, ovf_cnt, ovf, acc);

        const int n_tiles = (N_NODES + 63) / 64;
        final_kernel<<<n_tiles, 256, 0, stream>>>(feat, acc, W1, b1, W2, b2, out);
    } else {
        // Fallback: atomic scatter (R1 path) if ws is too small for CSR.
        float* acc = (float*)ws;
        hipMemsetAsync(acc, 0, (size_t)N_NODES * D * sizeof(float), stream);
        scatter_kernel<<<(N_EDGES * 64) / 256, 256, 0, stream>>>(emb, edge_src,
                                                                 edge_dst, acc);
        const int n_tiles = (N_NODES + 63) / 64;
        final_kernel<<<n_tiles, 256, 0, stream>>>(feat, acc, W1, b1, W2, b2, out);
    }
}

// Round 4
// 471.974 us; speedup vs baseline: 2.2702x; 1.9225x over previous
//
#include <hip/hip_runtime.h>

#define N_NODES 100000
#define N_EDGES 1600000
#define D 64
#define CAP 64        // slot cap per node; Poisson(16) deg, P(>64) astronomically small
#define OVF_CAP 8192  // overflow edge list capacity (practically unused)
#define N_TILES 1563  // (N_NODES + 63) / 64

// ws layout (bytes):
//   cnt      @ 0          : N_NODES int          (0.4 MB)
//   slots    @ 401408     : N_NODES*CAP int      (25.6 MB)  256B-aligned rows
//   acc      @ 26001408   : N_NODES*D float      (25.6 MB)
//   ovf_cnt  @ 51601408   : int
//   ovf      @ 51601424   : OVF_CAP int2
//   partials @ 51667200   : N_TILES*64 float     (0.4 MB)
#define WS_SLOTS_OFF  401408
#define WS_ACC_OFF    26001408
#define WS_OVFC_OFF   51601408
#define WS_OVF_OFF    51601424
#define WS_PART_OFF   51667200
#define WS_NEEDED     (WS_PART_OFF + N_TILES * 64 * 4)

// ---------------------------------------------------------------------------
// Build capped CSR: per edge, reserve a slot in dst's row. 1.6M int atomics
// (~16-way contention per node) instead of 102.4M f32 atomics.
// ---------------------------------------------------------------------------
__global__ __launch_bounds__(256) void fill_kernel(
    const int* __restrict__ edge_src, const int* __restrict__ edge_dst,
    int* __restrict__ cnt, int* __restrict__ slots,
    int* __restrict__ ovf_cnt, int2* __restrict__ ovf) {
    int e = blockIdx.x * 256 + threadIdx.x;  // grid sized exactly
    int s = edge_src[e];
    int d = edge_dst[e];
    int pos = atomicAdd(&cnt[d], 1);
    if (pos < CAP) {
        slots[d * CAP + pos] = s;
    } else {
        int i = atomicAdd(ovf_cnt, 1);
        if (i < OVF_CAP) ovf[i] = make_int2(s, d);
    }
}

// ---------------------------------------------------------------------------
// Atomic-free gather: one wave per node. One coalesced 256B read grabs the
// node's slot row; __shfl broadcasts each src; emb row reads are wave-uniform
// 256B loads (emb is 25.6MB -> L3-resident). Overwrites acc (no memset).
// ---------------------------------------------------------------------------
__global__ __launch_bounds__(256) void gather_kernel(
    const float* __restrict__ emb, const int* __restrict__ cnt,
    const int* __restrict__ slots, float* __restrict__ acc) {
    const int lane = threadIdx.x & 63;
    const int wave = threadIdx.x >> 6;
    const int v = blockIdx.x * 4 + wave;  // grid = N_NODES/4 exactly
    int deg = cnt[v];
    if (deg > CAP) deg = CAP;
    const int si = slots[v * CAP + lane];  // coalesced; lanes >= deg unused
    float sum = 0.f;
    int e = 0;
    for (; e + 4 <= deg; e += 4) {
        int s0 = __shfl(si, e);
        int s1 = __shfl(si, e + 1);
        int s2 = __shfl(si, e + 2);
        int s3 = __shfl(si, e + 3);
        float a0 = emb[s0 * D + lane];
        float a1 = emb[s1 * D + lane];
        float a2 = emb[s2 * D + lane];
        float a3 = emb[s3 * D + lane];
        sum += a0; sum += a1; sum += a2; sum += a3;
    }
    for (; e < deg; ++e) sum += emb[__shfl(si, e) * D + lane];
    acc[v * D + lane] = sum;
}

// Overflow edges (normally zero): runs AFTER gather, atomically adds into acc.
__global__ void ovf_kernel(const float* __restrict__ emb,
                           const int* __restrict__ ovf_cnt,
                           const int2* __restrict__ ovf,
                           float* __restrict__ acc) {
    int n = *ovf_cnt;
    if (n > OVF_CAP) n = OVF_CAP;
    int lane = threadIdx.x;
    for (int i = 0; i < n; ++i) {
        int2 e = ovf[i];
        unsafeAtomicAdd(&acc[e.y * D + lane], emb[e.x * D + lane]);
    }
}

// ---------------------------------------------------------------------------
// Fallback scatter (only if ws_size < WS_NEEDED): one wave per edge, 64 f32
// hardware atomics into acc. (Round-1 path.)
// ---------------------------------------------------------------------------
__global__ __launch_bounds__(256) void scatter_kernel(
    const float* __restrict__ emb,
    const int* __restrict__ edge_src, const int* __restrict__ edge_dst,
    float* __restrict__ acc) {
    int gid = blockIdx.x * 256 + threadIdx.x;
    int e = gid >> 6;
    int c = gid & 63;
    int s = edge_src[e];
    int d = edge_dst[e];
    unsafeAtomicAdd(&acc[d * D + c], emb[s * D + c]);
}

// ---------------------------------------------------------------------------
// Final pass. Per 64-node tile: z = feat@W1^T + nbr@W2^T; relu(z+b); column
// sums. R4 FIX: the R1/R3 epilogue did 100K f32 atomics into out[64] (4
// cache lines) -> L2 same-line serialization ~650us, invariant to the inner
// loop (R1 637us == R3 634us). Now each block stores its 64 partial sums to
// partials[block][*] with plain stores; reduce_kernel sums them.
// ---------------------------------------------------------------------------
__global__ __launch_bounds__(256) void final_kernel(
    const float* __restrict__ feat, const float* __restrict__ acc,
    const float* __restrict__ W1, const float* __restrict__ b1,
    const float* __restrict__ W2, const float* __restrict__ b2,
    float* __restrict__ partials) {
    __shared__ float ft[64][65];   // [k][node]
    __shared__ float nt[64][65];
    __shared__ float w1s[64 * 64]; // [o][k], read via uniform float4
    __shared__ float w2s[64 * 64];

    const int tid  = threadIdx.x;
    const int lane = tid & 63;
    const int wave = tid >> 6;
    const int ob   = wave * 16;  // this wave's output-column base
    const int node0 = blockIdx.x * 64;

    // Stage W1/W2: 64*64 floats = 1024 float4 each; 4 per thread, coalesced.
    {
        const float4* W1v = (const float4*)W1;
        const float4* W2v = (const float4*)W2;
        float4* w1v = (float4*)w1s;
        float4* w2v = (float4*)w2s;
#pragma unroll
        for (int i = 0; i < 4; ++i) {
            int idx = tid + i * 256;  // 0..1023
            w1v[idx] = W1v[idx];
            w2v[idx] = W2v[idx];
        }
    }

    // Stage feat/acc tiles, transposed. Within a wave: node fixed, c=lane ->
    // 256B coalesced global reads.
#pragma unroll 4
    for (int it = 0; it < 16; ++it) {
        const int r = wave + it * 4;
        const int node = node0 + r;
        float fv = 0.f, nv = 0.f;
        if (node < N_NODES) {
            fv = feat[node * D + lane];
            nv = acc[node * D + lane];
        }
        ft[lane][r] = fv;
        nt[lane][r] = nv;
    }
    __syncthreads();

    float z[16];
#pragma unroll
    for (int j = 0; j < 16; ++j) z[j] = 0.f;

    for (int k = 0; k < D; k += 4) {
        const float f0 = ft[k + 0][lane];
        const float f1 = ft[k + 1][lane];
        const float f2 = ft[k + 2][lane];
        const float f3 = ft[k + 3][lane];
        const float n0 = nt[k + 0][lane];
        const float n1 = nt[k + 1][lane];
        const float n2 = nt[k + 2][lane];
        const float n3 = nt[k + 3][lane];
#pragma unroll
        for (int j = 0; j < 16; ++j) {
            const float4 w1 = *(const float4*)&w1s[(ob + j) * 64 + k];
            const float4 w2 = *(const float4*)&w2s[(ob + j) * 64 + k];
            z[j] += f0 * w1.x + f1 * w1.y + f2 * w1.z + f3 * w1.w
                  + n0 * w2.x + n1 * w2.y + n2 * w2.z + n3 * w2.w;
        }
    }

    // Bias + ReLU + per-node accumulate (guard OOB nodes: bias alone can be
    // positive and must NOT contribute).
    float sums[16];
    const int node = node0 + lane;
#pragma unroll
    for (int j = 0; j < 16; ++j) {
        float u = z[j] + b1[ob + j] + b2[ob + j];
        u = (u > 0.f) ? u : 0.f;
        sums[j] = (node < N_NODES) ? u : 0.f;
    }

    // Reduce across 64 lanes; lane 0 stores the block partial (NO atomics).
#pragma unroll
    for (int j = 0; j < 16; ++j) {
        float v = sums[j];
        for (int off = 32; off > 0; off >>= 1) v += __shfl_down(v, off);
        if (lane == 0) partials[blockIdx.x * 64 + ob + j] = v;
    }
}

// ---------------------------------------------------------------------------
// Sum partials[N_TILES][64] -> out[64]. One block: thread t handles column
// t&63 over row segment t>>6 (4 segments of ~391 rows); coalesced reads
// (consecutive threads -> consecutive columns); LDS combine; 64 stores.
// ---------------------------------------------------------------------------
__global__ __launch_bounds__(256) void reduce_kernel(
    const float* __restrict__ partials, float* __restrict__ out) {
    __shared__ float red[4][64];
    const int col = threadIdx.x & 63;
    const int seg = threadIdx.x >> 6;
    const int rows_per_seg = (N_TILES + 3) / 4;  // 391
    const int r0 = seg * rows_per_seg;
    int r1 = r0 + rows_per_seg;
    if (r1 > N_TILES) r1 = N_TILES;
    float s = 0.f;
    for (int r = r0; r < r1; ++r) s += partials[r * 64 + col];
    red[seg][col] = s;
    __syncthreads();
    if (seg == 0) {
        out[col] = red[0][col] + red[1][col] + red[2][col] + red[3][col];
    }
}

extern "C" void kernel_launch(void* const* d_in, const int* in_sizes, int n_in,
                              void* d_out, int out_size, void* d_ws, size_t ws_size,
                              hipStream_t stream) {
    const float* feat = (const float*)d_in[0];
    const float* emb  = (const float*)d_in[1];
    const float* W1   = (const float*)d_in[2];
    const float* b1   = (const float*)d_in[3];
    const float* W2   = (const float*)d_in[4];
    const float* b2   = (const float*)d_in[5];
    const int* edge_src = (const int*)d_in[6];
    const int* edge_dst = (const int*)d_in[7];
    float* out = (float*)d_out;
    char* ws = (char*)d_ws;

    if (ws_size >= (size_t)WS_NEEDED) {
        int*   cnt      = (int*)ws;
        int*   slots    = (int*)(ws + WS_SLOTS_OFF);
        float* acc      = (float*)(ws + WS_ACC_OFF);
        int*   ovf_cnt  = (int*)(ws + WS_OVFC_OFF);
        int2*  ovf      = (int2*)(ws + WS_OVF_OFF);
        float* partials = (float*)(ws + WS_PART_OFF);

        hipMemsetAsync(cnt, 0, N_NODES * sizeof(int), stream);
        hipMemsetAsync(ovf_cnt, 0, sizeof(int), stream);

        fill_kernel<<<N_EDGES / 256, 256, 0, stream>>>(edge_src, edge_dst,
                                                       cnt, slots, ovf_cnt, ovf);
        gather_kernel<<<N_NODES / 4, 256, 0, stream>>>(emb, cnt, slots, acc);
        ovf_kernel<<<1, 64, 0, stream>>>(emb, ovf_cnt, ovf, acc);

        final_kernel<<<N_TILES, 256, 0, stream>>>(feat, acc, W1, b1, W2, b2,
                                                  partials);
        reduce_kernel<<<1, 256, 0, stream>>>(partials, out);
    } else {
        // Fallback: atomic scatter + atomic epilogue (R1 path, correct but slow).
        float* acc = (float*)ws;
        hipMemsetAsync(out, 0, D * sizeof(float), stream);
        hipMemsetAsync(acc, 0, (size_t)N_NODES * D * sizeof(float), stream);
        scatter_kernel<<<(N_EDGES * 64) / 256, 256, 0, stream>>>(emb, edge_src,
                                                                 edge_dst, acc);
        // Reuse final_kernel by treating out as a 1-tile partials buffer is
        // not valid here; instead run final into a temp region then reduce.
        float* partials = (float*)(ws + (size_t)N_NODES * D * sizeof(float));
        final_kernel<<<N_TILES, 256, 0, stream>>>(feat, acc, W1, b1, W2, b2,
                                                  partials);
        reduce_kernel<<<1, 256, 0, stream>>>(partials, out);
    }
}